// Round 11
// baseline (213.479 us; speedup 1.0000x reference)
//
#include <hip/hip_runtime.h>
#include <hip/hip_bf16.h>

#define N 8192
#define DIMS 128
#define NSLICE 32
#define SLICE_COLS (N / NSLICE)       // 256
#define SUBTILES (SLICE_COLS / 16)    // 16
#define NSTEPS (SUBTILES / 2)         // 8 (32 cols per step)
#define ROWS_PER_BLOCK 128
#define STRIPS 2                      // 16-row strips per wave (32 rows/wave)
#define NROWBLK (N / ROWS_PER_BLOCK)  // 64
#define NFIN 2048
#define MARGIN_F 0.2f
#define EPS_F 1e-6f
#define BIAS_F 512.0f                 // key' = 512 + sqj - 2dot > 0 (Cauchy-Schwarz)
#define META_LDS 16384                // after 2-deep 8KB double buffer
#define INF_F __builtin_huge_valf()

typedef __bf16 bf16x8 __attribute__((ext_vector_type(8)));
typedef float f32x4 __attribute__((ext_vector_type(4)));

// ws layout (bytes), ws_size = 256 MiB:
//   Xb   : ushort[N*DIMS]    @ 0         (2 MiB)   bf16 features (256B/row)
//   meta : float2[N]         @ 2097152   (64 KiB)  {sq+512, label bits}
//   part : uint2[NSLICE*N]   @ 2162688   (2 MiB)   packed {max_pos_u, min_neg_u}
//   bsum : float2[NFIN]      @ 4259840   (16 KiB)
#define XB_OFF   0
#define META_OFF 2097152
#define PART_OFF 2162688
#define BSUM_OFF 4259840

#define GLD_LDS(g, l) \
  __builtin_amdgcn_global_load_lds( \
      (const __attribute__((address_space(1))) void*)(g), \
      (__attribute__((address_space(3))) void*)(l), 16, 0, 0)

// ---------------- prep: fp32 -> bf16, row sq-norm(+bias), pack label ------
__global__ __launch_bounds__(256) void prep_kernel(
    const float* __restrict__ feat, const int* __restrict__ lab,
    unsigned short* __restrict__ Xb, float2* __restrict__ meta) {
  int row = blockIdx.x * 4 + (threadIdx.x >> 6);
  int lane = threadIdx.x & 63;
  float2 x = *reinterpret_cast<const float2*>(feat + (size_t)row * DIMS + lane * 2);
  __hip_bfloat16 hx = __float2bfloat16(x.x);
  __hip_bfloat16 hy = __float2bfloat16(x.y);
  unsigned short ux, uy;
  __builtin_memcpy(&ux, &hx, 2);
  __builtin_memcpy(&uy, &hy, 2);
  unsigned int packed = (unsigned int)ux | ((unsigned int)uy << 16);
  *reinterpret_cast<unsigned int*>(Xb + (size_t)row * DIMS + lane * 2) = packed;
  float s = x.x * x.x + x.y * x.y;
#pragma unroll
  for (int m = 32; m >= 1; m >>= 1) s += __shfl_xor(s, m, 64);
  if (lane == 0) meta[row] = make_float2(s + BIAS_F, __int_as_float(lab[row]));
}

// ---------------- mine: max-occupancy LDS-staged MFMA + packed mining -----
// grid = NROWBLK*NSLICE = 2048 blocks -> 8 blocks/CU (18KB LDS), 32 waves/CU
// at VGPR<=64 (launch_bounds(256,8); probe r10 measured this structure
// compiles to 64 naturally). r10 ablation: wall is latency/TLP, not barrier
// structure -> proven r4/r5 full-drain double-buffer loop; per-block drain
// convoys overlap across the 8 independent resident blocks.
__global__ __launch_bounds__(256, 8) void mine_kernel(
    const unsigned short* __restrict__ Xb, const float2* __restrict__ meta,
    const int* __restrict__ lab, uint2* __restrict__ part) {
  __shared__ char smem[2 * 8192 + 2048];  // double buffer + slice meta

  int rb = blockIdx.x / NSLICE;
  int sl = blockIdx.x % NSLICE;
  int tid = threadIdx.x;
  int wave = tid >> 6;
  int lane = tid & 63;
  int lrow = lane & 15;  // B-col / C-col lane index
  int lk = lane >> 4;    // k-subgroup; also C-row group
  int rowbase = rb * ROWS_PER_BLOCK + wave * (STRIPS * 16);
  int j0 = sl * SLICE_COLS;

  // --- stage slice meta (256 * 8B = 2KB) once: waves 0,1 ---
  if (wave < 2) {
    const char* g = (const char*)meta + (size_t)j0 * 8 + tid * 16;
    char* l = smem + META_LDS + wave * 1024;
    GLD_LDS(g, l);
  }
  // --- B staging: thread tid -> (colt = tid>>4, chunk = tid&15).
  // LDS slot col*256 + chunk*16 holds global chunk (chunk^(col&7)) of the
  // col's row (involution swizzle; col&7 invariant under +16/+32 col steps).
  int colt = tid >> 4;
  int chunk = tid & 15;
  const char* gsrc0 = (const char*)Xb + (size_t)(j0 + colt) * 256 +
                      ((chunk ^ (colt & 7)) * 16);
  {  // stage step 0 into buf 0
    GLD_LDS(gsrc0, smem + wave * 1024);
    GLD_LDS(gsrc0 + 4096, smem + 4096 + wave * 1024);
  }

  // --- A fragments: STRIPS x 4 k-groups, registers for the whole scan ---
  bf16x8 afrag[STRIPS][4];
#pragma unroll
  for (int s = 0; s < STRIPS; ++s) {
    const unsigned short* rp = Xb + (size_t)(rowbase + s * 16 + lrow) * DIMS;
#pragma unroll
    for (int g = 0; g < 4; ++g)
      afrag[s][g] = *reinterpret_cast<const bf16x8*>(rp + g * 32 + lk * 8);
  }
  int4 labi[STRIPS];
#pragma unroll
  for (int s = 0; s < STRIPS; ++s)
    labi[s] = *reinterpret_cast<const int4*>(lab + rowbase + s * 16 + lk * 4);

  unsigned int bpu[STRIPS][4], bnu[STRIPS][4];
#pragma unroll
  for (int s = 0; s < STRIPS; ++s)
#pragma unroll
    for (int e = 0; e < 4; ++e) { bpu[s][e] = 0u; bnu[s][e] = 0xFFFFFFFFu; }

  // per-lane swizzled B-frag LDS byte offsets (hoisted)
  int boff[4];
#pragma unroll
  for (int g = 0; g < 4; ++g)
    boff[g] = lrow * 256 + (((g * 4 + lk) ^ (lrow & 7)) * 16);

  __syncthreads();  // meta + step0 staged

  for (int it = 0; it < NSTEPS; ++it) {
    int cur = it & 1;
    if (it + 1 < NSTEPS) {  // uniform branch: prefetch step it+1
      const char* g = gsrc0 + (size_t)(it + 1) * 8192;
      char* l = smem + (cur ^ 1) * 8192 + wave * 1024;
      GLD_LDS(g, l);
      GLD_LDS(g + 4096, l + 4096);
    }

#pragma unroll
    for (int h = 0; h < 2; ++h) {
      int t = it * 2 + h;
      float2 mcur =
          *reinterpret_cast<const float2*>(smem + META_LDS + t * 128 + lrow * 8);
      float sqjB = mcur.x;  // sq_j + 512
      int labj = __float_as_int(mcur.y);
      unsigned int ju = (unsigned int)(j0 + t * 16 + lrow);

      const char* bbase = smem + cur * 8192 + h * 4096;
      bf16x8 bb[4];
#pragma unroll
      for (int g = 0; g < 4; ++g)
        bb[g] = *reinterpret_cast<const bf16x8*>(bbase + boff[g]);

#pragma unroll
      for (int s = 0; s < STRIPS; ++s) {
        f32x4 acc = {0.f, 0.f, 0.f, 0.f};
#pragma unroll
        for (int g = 0; g < 4; ++g)
          acc = __builtin_amdgcn_mfma_f32_16x16x32_bf16(afrag[s][g], bb[g], acc,
                                                        0, 0, 0);
        int labs[4] = {labi[s].x, labi[s].y, labi[s].z, labi[s].w};
#pragma unroll
        for (int e = 0; e < 4; ++e) {
          float key = fmaf(-2.0f, acc[e], sqjB);  // 512 + d^2 - sq_i > 0
          unsigned int u = (__float_as_uint(key) & 0xFFFFE000u) | ju;
          bool pos = (labj == labs[e]);
          unsigned int up = pos ? u : 0u;
          unsigned int un = pos ? 0xFFFFFFFFu : u;
          bpu[s][e] = max(bpu[s][e], up);
          bnu[s][e] = min(bnu[s][e], un);
        }
      }
    }
    // drains stage-loads (vmcnt) + ds_reads (lgkm), then barrier.
    __syncthreads();
  }

  // merge across the 16 lanes that share each C-row (lane bits 0-3)
#pragma unroll
  for (int s = 0; s < STRIPS; ++s) {
#pragma unroll
    for (int e = 0; e < 4; ++e) {
      unsigned int pu = bpu[s][e], nu = bnu[s][e];
#pragma unroll
      for (int m = 1; m < 16; m <<= 1) {
        pu = max(pu, (unsigned int)__shfl_xor((int)pu, m, 64));
        nu = min(nu, (unsigned int)__shfl_xor((int)nu, m, 64));
      }
      if (lrow == 0) {
        int row = rowbase + s * 16 + lk * 4 + e;
        part[(size_t)sl * N + row] = make_uint2(pu, nu);
      }
    }
  }
}

// ---------------- finalize: wave-per-anchor merge + exact fp32 hinge ------
__global__ __launch_bounds__(256) void finalize_kernel(
    const float* __restrict__ feat, const uint2* __restrict__ part,
    float2* __restrict__ bsum) {
  int wave = threadIdx.x >> 6, lane = threadIdx.x & 63;
  int i = blockIdx.x * 4 + wave;

  unsigned int pu = 0u, nu = 0xFFFFFFFFu;
  if (lane < NSLICE) {
    uint2 p = part[(size_t)lane * N + i];
    pu = p.x; nu = p.y;
  }
#pragma unroll
  for (int m = 1; m < NSLICE; m <<= 1) {
    pu = max(pu, (unsigned int)__shfl_xor((int)pu, m, 64));
    nu = min(nu, (unsigned int)__shfl_xor((int)nu, m, 64));
  }
  pu = (unsigned int)__shfl((int)pu, 0, 64);
  nu = (unsigned int)__shfl((int)nu, 0, 64);
  bool valid = (nu != 0xFFFFFFFFu);
  int pi = (int)(pu & 8191u);
  int ni = (int)(nu & 8191u);

  float2 av = *reinterpret_cast<const float2*>(feat + (size_t)i * DIMS + lane * 2);
  float2 pw = *reinterpret_cast<const float2*>(feat + (size_t)pi * DIMS + lane * 2);
  float2 nw = *reinterpret_cast<const float2*>(feat + (size_t)ni * DIMS + lane * 2);
  float d0 = av.x - pw.x + EPS_F, d1 = av.y - pw.y + EPS_F;
  float sp = fmaf(d0, d0, d1 * d1);
  float e0 = av.x - nw.x + EPS_F, e1 = av.y - nw.y + EPS_F;
  float sn = fmaf(e0, e0, e1 * e1);
#pragma unroll
  for (int m = 32; m >= 1; m >>= 1) {
    sp += __shfl_xor(sp, m, 64);
    sn += __shfl_xor(sn, m, 64);
  }

  __shared__ float s_s[4], s_c[4];
  if (lane == 0) {
    float per = sqrtf(sp) - sqrtf(sn) + MARGIN_F;
    per = per > 0.f ? per : 0.f;
    per = valid ? per : 0.f;
    s_s[wave] = per;
    s_c[wave] = valid ? 1.f : 0.f;
  }
  __syncthreads();
  if (threadIdx.x == 0) {
    float ts = (s_s[0] + s_s[1]) + (s_s[2] + s_s[3]);
    float tc = (s_c[0] + s_c[1]) + (s_c[2] + s_c[3]);
    bsum[blockIdx.x] = make_float2(ts, tc);
  }
}

__global__ __launch_bounds__(256) void final_reduce_kernel(
    const float2* __restrict__ bsum, float* __restrict__ out) {
  int t = threadIdx.x;
  float s = 0.f, c = 0.f;
#pragma unroll
  for (int k = 0; k < NFIN / 256; ++k) {
    float2 v = bsum[t + k * 256];
    s += v.x; c += v.y;
  }
#pragma unroll
  for (int m = 32; m >= 1; m >>= 1) {
    s += __shfl_xor(s, m, 64);
    c += __shfl_xor(c, m, 64);
  }
  __shared__ float s_s[4], s_c[4];
  int wave = t >> 6, lane = t & 63;
  if (lane == 0) { s_s[wave] = s; s_c[wave] = c; }
  __syncthreads();
  if (t == 0) {
    float ts = (s_s[0] + s_s[1]) + (s_s[2] + s_s[3]);
    float tc = (s_c[0] + s_c[1]) + (s_c[2] + s_c[3]);
    out[0] = (tc > 0.f) ? (ts / tc) : 0.f;
  }
}

extern "C" void kernel_launch(void* const* d_in, const int* in_sizes, int n_in,
                              void* d_out, int out_size, void* d_ws, size_t ws_size,
                              hipStream_t stream) {
  const float* feat = (const float*)d_in[0];
  const int* lab = (const int*)d_in[1];
  char* ws = (char*)d_ws;
  unsigned short* Xb = (unsigned short*)(ws + XB_OFF);
  float2* meta = (float2*)(ws + META_OFF);
  uint2* part = (uint2*)(ws + PART_OFF);
  float2* bsum = (float2*)(ws + BSUM_OFF);
  float* out = (float*)d_out;

  prep_kernel<<<N / 4, 256, 0, stream>>>(feat, lab, Xb, meta);
  mine_kernel<<<NROWBLK * NSLICE, 256, 0, stream>>>(Xb, meta, lab, part);
  finalize_kernel<<<N / 4, 256, 0, stream>>>(feat, part, bsum);
  final_reduce_kernel<<<1, 256, 0, stream>>>(bsum, out);
}

// Round 12
// 46.263 us; speedup vs baseline: 4.6145x; 4.6145x over previous
//
#include <hip/hip_runtime.h>
#include <hip/hip_bf16.h>

#define N 8192
#define DIMS 128
#define NSLICE 32
#define SLICE_COLS (N / NSLICE)       // 256
#define SUBTILES (SLICE_COLS / 16)    // 16
#define NSTEPS (SUBTILES / 2)         // 8 (32 cols per step)
#define ROWS_PER_BLOCK 128
#define STRIPS 2                      // 16-row strips per wave (32 rows/wave)
#define NROWBLK (N / ROWS_PER_BLOCK)  // 64
#define NFIN 2048
#define MARGIN_F 0.2f
#define EPS_F 1e-6f
#define BIAS_F 512.0f                 // key' = 512 + sqj - 2dot > 0 (Cauchy-Schwarz)
#define META_LDS 16384                // after 2-deep 8KB double buffer
#define INF_F __builtin_huge_valf()

typedef __bf16 bf16x8 __attribute__((ext_vector_type(8)));
typedef float f32x4 __attribute__((ext_vector_type(4)));

// ws layout (bytes), ws_size = 256 MiB:
//   Xb   : ushort[N*DIMS]    @ 0         (2 MiB)   bf16 features (256B/row)
//   meta : float2[N]         @ 2097152   (64 KiB)  {sq+512, label bits}
//   part : uint2[NSLICE*N]   @ 2162688   (2 MiB)   packed {max_pos_u, min_neg_u}
//   bsum : float2[NFIN]      @ 4259840   (16 KiB)
#define XB_OFF   0
#define META_OFF 2097152
#define PART_OFF 2162688
#define BSUM_OFF 4259840

#define GLD_LDS(g, l) \
  __builtin_amdgcn_global_load_lds( \
      (const __attribute__((address_space(1))) void*)(g), \
      (__attribute__((address_space(3))) void*)(l), 16, 0, 0)

// ---------------- prep: fp32 -> bf16, row sq-norm(+bias), pack label ------
__global__ __launch_bounds__(256) void prep_kernel(
    const float* __restrict__ feat, const int* __restrict__ lab,
    unsigned short* __restrict__ Xb, float2* __restrict__ meta) {
  int row = blockIdx.x * 4 + (threadIdx.x >> 6);
  int lane = threadIdx.x & 63;
  float2 x = *reinterpret_cast<const float2*>(feat + (size_t)row * DIMS + lane * 2);
  __hip_bfloat16 hx = __float2bfloat16(x.x);
  __hip_bfloat16 hy = __float2bfloat16(x.y);
  unsigned short ux, uy;
  __builtin_memcpy(&ux, &hx, 2);
  __builtin_memcpy(&uy, &hy, 2);
  unsigned int packed = (unsigned int)ux | ((unsigned int)uy << 16);
  *reinterpret_cast<unsigned int*>(Xb + (size_t)row * DIMS + lane * 2) = packed;
  float s = x.x * x.x + x.y * x.y;
#pragma unroll
  for (int m = 32; m >= 1; m >>= 1) s += __shfl_xor(s, m, 64);
  if (lane == 0) meta[row] = make_float2(s + BIAS_F, __int_as_float(lab[row]));
}

// ---------------- mine: max-occupancy LDS-staged MFMA + packed mining -----
// grid = NROWBLK*NSLICE = 2048 blocks, 18KB LDS, launch_bounds(256,4).
// r10 probe: THIS structure at (256,4) compiles to 64 VGPR naturally -> the
// HW can co-schedule 8 blocks/CU (32 waves/CU) since occupancy follows the
// ACTUAL 64-reg allocation, not the bound. r11 lesson: forcing (256,8)
// makes the allocator compile to 32 regs and spill 800MB to scratch.
__global__ __launch_bounds__(256, 4) void mine_kernel(
    const unsigned short* __restrict__ Xb, const float2* __restrict__ meta,
    const int* __restrict__ lab, uint2* __restrict__ part) {
  __shared__ char smem[2 * 8192 + 2048];  // double buffer + slice meta

  int rb = blockIdx.x / NSLICE;
  int sl = blockIdx.x % NSLICE;
  int tid = threadIdx.x;
  int wave = tid >> 6;
  int lane = tid & 63;
  int lrow = lane & 15;  // B-col / C-col lane index
  int lk = lane >> 4;    // k-subgroup; also C-row group
  int rowbase = rb * ROWS_PER_BLOCK + wave * (STRIPS * 16);
  int j0 = sl * SLICE_COLS;

  // --- stage slice meta (256 * 8B = 2KB) once: waves 0,1 ---
  if (wave < 2) {
    const char* g = (const char*)meta + (size_t)j0 * 8 + tid * 16;
    char* l = smem + META_LDS + wave * 1024;
    GLD_LDS(g, l);
  }
  // --- B staging: thread tid -> (colt = tid>>4, chunk = tid&15).
  // LDS slot col*256 + chunk*16 holds global chunk (chunk^(col&7)) of the
  // col's row (involution swizzle; col&7 invariant under +16/+32 col steps).
  int colt = tid >> 4;
  int chunk = tid & 15;
  const char* gsrc0 = (const char*)Xb + (size_t)(j0 + colt) * 256 +
                      ((chunk ^ (colt & 7)) * 16);
  {  // stage step 0 into buf 0
    GLD_LDS(gsrc0, smem + wave * 1024);
    GLD_LDS(gsrc0 + 4096, smem + 4096 + wave * 1024);
  }

  // --- A fragments: STRIPS x 4 k-groups, registers for the whole scan ---
  bf16x8 afrag[STRIPS][4];
#pragma unroll
  for (int s = 0; s < STRIPS; ++s) {
    const unsigned short* rp = Xb + (size_t)(rowbase + s * 16 + lrow) * DIMS;
#pragma unroll
    for (int g = 0; g < 4; ++g)
      afrag[s][g] = *reinterpret_cast<const bf16x8*>(rp + g * 32 + lk * 8);
  }
  int4 labi[STRIPS];
#pragma unroll
  for (int s = 0; s < STRIPS; ++s)
    labi[s] = *reinterpret_cast<const int4*>(lab + rowbase + s * 16 + lk * 4);

  unsigned int bpu[STRIPS][4], bnu[STRIPS][4];
#pragma unroll
  for (int s = 0; s < STRIPS; ++s)
#pragma unroll
    for (int e = 0; e < 4; ++e) { bpu[s][e] = 0u; bnu[s][e] = 0xFFFFFFFFu; }

  // per-lane swizzled B-frag LDS byte offsets (hoisted)
  int boff[4];
#pragma unroll
  for (int g = 0; g < 4; ++g)
    boff[g] = lrow * 256 + (((g * 4 + lk) ^ (lrow & 7)) * 16);

  __syncthreads();  // meta + step0 staged

  for (int it = 0; it < NSTEPS; ++it) {
    int cur = it & 1;
    if (it + 1 < NSTEPS) {  // uniform branch: prefetch step it+1
      const char* g = gsrc0 + (size_t)(it + 1) * 8192;
      char* l = smem + (cur ^ 1) * 8192 + wave * 1024;
      GLD_LDS(g, l);
      GLD_LDS(g + 4096, l + 4096);
    }

#pragma unroll
    for (int h = 0; h < 2; ++h) {
      int t = it * 2 + h;
      float2 mcur =
          *reinterpret_cast<const float2*>(smem + META_LDS + t * 128 + lrow * 8);
      float sqjB = mcur.x;  // sq_j + 512
      int labj = __float_as_int(mcur.y);
      unsigned int ju = (unsigned int)(j0 + t * 16 + lrow);

      const char* bbase = smem + cur * 8192 + h * 4096;
      bf16x8 bb[4];
#pragma unroll
      for (int g = 0; g < 4; ++g)
        bb[g] = *reinterpret_cast<const bf16x8*>(bbase + boff[g]);

#pragma unroll
      for (int s = 0; s < STRIPS; ++s) {
        f32x4 acc = {0.f, 0.f, 0.f, 0.f};
#pragma unroll
        for (int g = 0; g < 4; ++g)
          acc = __builtin_amdgcn_mfma_f32_16x16x32_bf16(afrag[s][g], bb[g], acc,
                                                        0, 0, 0);
        int labs[4] = {labi[s].x, labi[s].y, labi[s].z, labi[s].w};
#pragma unroll
        for (int e = 0; e < 4; ++e) {
          float key = fmaf(-2.0f, acc[e], sqjB);  // 512 + d^2 - sq_i > 0
          unsigned int u = (__float_as_uint(key) & 0xFFFFE000u) | ju;
          bool pos = (labj == labs[e]);
          unsigned int up = pos ? u : 0u;
          unsigned int un = pos ? 0xFFFFFFFFu : u;
          bpu[s][e] = max(bpu[s][e], up);
          bnu[s][e] = min(bnu[s][e], un);
        }
      }
    }
    // drains stage-loads (vmcnt) + ds_reads (lgkm), then barrier.
    __syncthreads();
  }

  // merge across the 16 lanes that share each C-row (lane bits 0-3)
#pragma unroll
  for (int s = 0; s < STRIPS; ++s) {
#pragma unroll
    for (int e = 0; e < 4; ++e) {
      unsigned int pu = bpu[s][e], nu = bnu[s][e];
#pragma unroll
      for (int m = 1; m < 16; m <<= 1) {
        pu = max(pu, (unsigned int)__shfl_xor((int)pu, m, 64));
        nu = min(nu, (unsigned int)__shfl_xor((int)nu, m, 64));
      }
      if (lrow == 0) {
        int row = rowbase + s * 16 + lk * 4 + e;
        part[(size_t)sl * N + row] = make_uint2(pu, nu);
      }
    }
  }
}

// ---------------- finalize: wave-per-anchor merge + exact fp32 hinge ------
__global__ __launch_bounds__(256) void finalize_kernel(
    const float* __restrict__ feat, const uint2* __restrict__ part,
    float2* __restrict__ bsum) {
  int wave = threadIdx.x >> 6, lane = threadIdx.x & 63;
  int i = blockIdx.x * 4 + wave;

  unsigned int pu = 0u, nu = 0xFFFFFFFFu;
  if (lane < NSLICE) {
    uint2 p = part[(size_t)lane * N + i];
    pu = p.x; nu = p.y;
  }
#pragma unroll
  for (int m = 1; m < NSLICE; m <<= 1) {
    pu = max(pu, (unsigned int)__shfl_xor((int)pu, m, 64));
    nu = min(nu, (unsigned int)__shfl_xor((int)nu, m, 64));
  }
  pu = (unsigned int)__shfl((int)pu, 0, 64);
  nu = (unsigned int)__shfl((int)nu, 0, 64);
  bool valid = (nu != 0xFFFFFFFFu);
  int pi = (int)(pu & 8191u);
  int ni = (int)(nu & 8191u);

  float2 av = *reinterpret_cast<const float2*>(feat + (size_t)i * DIMS + lane * 2);
  float2 pw = *reinterpret_cast<const float2*>(feat + (size_t)pi * DIMS + lane * 2);
  float2 nw = *reinterpret_cast<const float2*>(feat + (size_t)ni * DIMS + lane * 2);
  float d0 = av.x - pw.x + EPS_F, d1 = av.y - pw.y + EPS_F;
  float sp = fmaf(d0, d0, d1 * d1);
  float e0 = av.x - nw.x + EPS_F, e1 = av.y - nw.y + EPS_F;
  float sn = fmaf(e0, e0, e1 * e1);
#pragma unroll
  for (int m = 32; m >= 1; m >>= 1) {
    sp += __shfl_xor(sp, m, 64);
    sn += __shfl_xor(sn, m, 64);
  }

  __shared__ float s_s[4], s_c[4];
  if (lane == 0) {
    float per = sqrtf(sp) - sqrtf(sn) + MARGIN_F;
    per = per > 0.f ? per : 0.f;
    per = valid ? per : 0.f;
    s_s[wave] = per;
    s_c[wave] = valid ? 1.f : 0.f;
  }
  __syncthreads();
  if (threadIdx.x == 0) {
    float ts = (s_s[0] + s_s[1]) + (s_s[2] + s_s[3]);
    float tc = (s_c[0] + s_c[1]) + (s_c[2] + s_c[3]);
    bsum[blockIdx.x] = make_float2(ts, tc);
  }
}

__global__ __launch_bounds__(256) void final_reduce_kernel(
    const float2* __restrict__ bsum, float* __restrict__ out) {
  int t = threadIdx.x;
  float s = 0.f, c = 0.f;
#pragma unroll
  for (int k = 0; k < NFIN / 256; ++k) {
    float2 v = bsum[t + k * 256];
    s += v.x; c += v.y;
  }
#pragma unroll
  for (int m = 32; m >= 1; m >>= 1) {
    s += __shfl_xor(s, m, 64);
    c += __shfl_xor(c, m, 64);
  }
  __shared__ float s_s[4], s_c[4];
  int wave = t >> 6, lane = t & 63;
  if (lane == 0) { s_s[wave] = s; s_c[wave] = c; }
  __syncthreads();
  if (t == 0) {
    float ts = (s_s[0] + s_s[1]) + (s_s[2] + s_s[3]);
    float tc = (s_c[0] + s_c[1]) + (s_c[2] + s_c[3]);
    out[0] = (tc > 0.f) ? (ts / tc) : 0.f;
  }
}

extern "C" void kernel_launch(void* const* d_in, const int* in_sizes, int n_in,
                              void* d_out, int out_size, void* d_ws, size_t ws_size,
                              hipStream_t stream) {
  const float* feat = (const float*)d_in[0];
  const int* lab = (const int*)d_in[1];
  char* ws = (char*)d_ws;
  unsigned short* Xb = (unsigned short*)(ws + XB_OFF);
  float2* meta = (float2*)(ws + META_OFF);
  uint2* part = (uint2*)(ws + PART_OFF);
  float2* bsum = (float2*)(ws + BSUM_OFF);
  float* out = (float*)d_out;

  prep_kernel<<<N / 4, 256, 0, stream>>>(feat, lab, Xb, meta);
  mine_kernel<<<NROWBLK * NSLICE, 256, 0, stream>>>(Xb, meta, lab, part);
  finalize_kernel<<<N / 4, 256, 0, stream>>>(feat, part, bsum);
  final_reduce_kernel<<<1, 256, 0, stream>>>(bsum, out);
}